// Round 1
// baseline (12424.749 us; speedup 1.0000x reference)
//
#include <hip/hip_runtime.h>
#include <math.h>

// ---------------- problem constants ----------------
constexpr int NLAYER = 6;
constexpr int NHEAD  = 8;
constexpr int HDIM   = 512;
constexpr int FDIM   = 2048;
constexpr int SEQ    = 1024;   // SE == SD
constexpr int EDIM   = 128;
constexpr int BATCH  = 4;
constexpr int DHEAD  = 64;     // HDIM / NHEAD
constexpr int VD     = 32000;
constexpr float EPSV = 1e-6f;
constexpr float NEGV = -1e9f;

constexpr int NROWS = BATCH * SEQ;          // 4096
constexpr size_t SB = (size_t)NROWS * HDIM; // 2M floats per [B,S,H] buffer

// ---------------- gather: out[r,:] = emb[idx[r],:] ----------------
__global__ void k_gather(const int* __restrict__ idx, const float* __restrict__ emb,
                         float* __restrict__ out) {
    int r = blockIdx.x;
    int t = threadIdx.x;               // 0..127 (EDIM)
    out[(size_t)r * EDIM + t] = emb[(size_t)idx[r] * EDIM + t];
}

// ---------------- add positional: out = x + pos (pos broadcast over batch) ----------------
__global__ __launch_bounds__(256) void k_addpos(const float4* __restrict__ x,
                                                const float4* __restrict__ pos,
                                                float4* __restrict__ o) {
    int i = blockIdx.x * 256 + threadIdx.x;          // covers B*SEQ*HDIM/4 exactly
    int pi = i & (SEQ * HDIM / 4 - 1);               // power of 2
    float4 a = x[i], p = pos[pi];
    o[i] = make_float4(a.x + p.x, a.y + p.y, a.z + p.z, a.w + p.w);
}

// ---------------- fused LayerNorm + residual: out = res + LN(x)*scale + bias ----------------
__global__ __launch_bounds__(256) void k_lnadd(const float* __restrict__ x,
                                               const float* __restrict__ res,
                                               const float* __restrict__ scale,
                                               const float* __restrict__ bias,
                                               float* __restrict__ out) {
    int row = blockIdx.x;
    int t = threadIdx.x;
    const float* xr = x + (size_t)row * HDIM;
    float x0 = xr[t], x1 = xr[t + 256];
    float s = x0 + x1;
    float sq = x0 * x0 + x1 * x1;
#pragma unroll
    for (int m = 1; m < 64; m <<= 1) {
        s  += __shfl_xor(s, m);
        sq += __shfl_xor(sq, m);
    }
    __shared__ float red[8];
    int w = t >> 6;
    if ((t & 63) == 0) { red[w] = s; red[4 + w] = sq; }
    __syncthreads();
    s  = red[0] + red[1] + red[2] + red[3];
    sq = red[4] + red[5] + red[6] + red[7];
    float mu  = s * (1.0f / HDIM);
    float var = fmaxf(sq * (1.0f / HDIM) - mu * mu, 0.0f);
    float rs  = 1.0f / sqrtf(var + EPSV);
    const float* rr = res + (size_t)row * HDIM;
    float* orow = out + (size_t)row * HDIM;
    orow[t]       = rr[t]       + (x0 - mu) * rs * scale[t]       + bias[t];
    orow[t + 256] = rr[t + 256] + (x1 - mu) * rs * scale[t + 256] + bias[t + 256];
}

// ---------------- tiled SGEMM: C[M,N] = alpha*(A[M,K] @ W[K,N]) (+bias[N]) (ReLU) ----------------
// BM=BN=64, BK=16, 256 threads, 4x4 micro-tile. M%64==0, N%64==0, K%16==0.
constexpr int BM = 64, BN = 64, BK = 16;
__global__ __launch_bounds__(256) void k_sgemm(const float* __restrict__ A,
                                               const float* __restrict__ Wm,
                                               float* __restrict__ C,
                                               int M, int N, int K,
                                               const float* __restrict__ bias,
                                               float alpha, int relu) {
    __shared__ float As[BK][BM];
    __shared__ float Bs[BK][BN];
    int tid = threadIdx.x;
    int tx = tid & 15, ty = tid >> 4;
    int m0 = blockIdx.y * BM, n0 = blockIdx.x * BN;

    int arow = tid >> 2;            // 0..63
    int aq   = (tid & 3) * 4;       // 0,4,8,12
    int brow = tid >> 4;            // 0..15
    int bq   = (tid & 15) * 4;      // 0..60

    const float* Ap = A + (size_t)(m0 + arow) * K + aq;
    const float* Bp = Wm + (size_t)brow * N + n0 + bq;

    float acc[4][4] = {};
    for (int k0 = 0; k0 < K; k0 += BK) {
        float4 av = *(const float4*)(Ap + k0);
        float4 bv = *(const float4*)(Bp + (size_t)k0 * N);
        As[aq + 0][arow] = av.x;
        As[aq + 1][arow] = av.y;
        As[aq + 2][arow] = av.z;
        As[aq + 3][arow] = av.w;
        *(float4*)&Bs[brow][bq] = bv;
        __syncthreads();
#pragma unroll
        for (int kk = 0; kk < BK; ++kk) {
            float4 a = *(const float4*)&As[kk][ty * 4];
            float4 b = *(const float4*)&Bs[kk][tx * 4];
            float ar[4] = {a.x, a.y, a.z, a.w};
            float br[4] = {b.x, b.y, b.z, b.w};
#pragma unroll
            for (int i = 0; i < 4; ++i)
#pragma unroll
                for (int j = 0; j < 4; ++j)
                    acc[i][j] = fmaf(ar[i], br[j], acc[i][j]);
        }
        __syncthreads();
    }
    // epilogue
#pragma unroll
    for (int i = 0; i < 4; ++i) {
        int row = m0 + ty * 4 + i;
        int col = n0 + tx * 4;
        float4 v;
        float* vv = (float*)&v;
#pragma unroll
        for (int j = 0; j < 4; ++j) {
            float t = acc[i][j] * alpha;
            if (bias) t += bias[col + j];
            if (relu) t = fmaxf(t, 0.0f);
            vv[j] = t;
        }
        *(float4*)&C[(size_t)row * N + col] = v;
    }
}

// ---------------- flash attention (fp32, online softmax) ----------------
// Q,K,V,O layout: [B, S, NHEAD, DHEAD] flattened ([B,S,H] head-major).
// grid: (Sq/32, B*NHEAD), block 256. QB=32 q-rows per block, KB=64 keys per tile.
constexpr int QB = 32, KB = 64;
constexpr int LDK = DHEAD + 4;   // 68: pad kills stride-64 bank conflicts, keeps 16B align
__global__ __launch_bounds__(256) void k_flash(const float* __restrict__ Qg,
                                               const float* __restrict__ Kg,
                                               const float* __restrict__ Vg,
                                               float* __restrict__ O,
                                               int Sq, int Skv, int causal) {
    __shared__ float Qs[QB][LDK];
    __shared__ float Ks[KB][LDK];
    __shared__ float Vs[KB][LDK];
    __shared__ float Ps[QB][LDK];

    int tid = threadIdx.x;
    int qb = blockIdx.x, bh = blockIdx.y;
    int bb = bh >> 3, hh = bh & 7;      // NHEAD == 8
    int q0 = qb * QB;
    int qr  = tid >> 3;                 // 0..31  (q row within block)
    int sub = tid & 7;                  // 0..7   (k-group in phase B, d-group in phase D)

    // load Q block: 8 floats per thread
    {
        const float* qrow = Qg + (((size_t)(bb * Sq + q0 + qr)) * NHEAD + hh) * DHEAD + sub * 8;
        *(float4*)&Qs[qr][sub * 8]     = *(const float4*)qrow;
        *(float4*)&Qs[qr][sub * 8 + 4] = *(const float4*)(qrow + 4);
    }

    float m_prev = -INFINITY, l_prev = 0.0f;
    float o[8] = {};

    int ntile = Skv / KB;
    if (causal) ntile = (q0 + QB - 1) / KB + 1;

    for (int t0 = 0; t0 < ntile; ++t0) {
        int k0 = t0 * KB;
        __syncthreads();   // previous-iter readers done (also orders the Qs store once)
        // load K,V tiles: 64x64 each, 4 float4 per thread per tensor
        {
            int r  = tid >> 4;             // 0..15
            int cq = (tid & 15) * 4;       // 0..60
#pragma unroll
            for (int it = 0; it < 4; ++it) {
                int rr2 = r + it * 16;
                size_t gro = (((size_t)(bb * Skv + k0 + rr2)) * NHEAD + hh) * DHEAD + cq;
                *(float4*)&Ks[rr2][cq] = *(const float4*)(Kg + gro);
                *(float4*)&Vs[rr2][cq] = *(const float4*)(Vg + gro);
            }
        }
        __syncthreads();

        // phase B: scores for kc = sub + 8*j  (j=0..7)
        float sc[8] = {};
#pragma unroll
        for (int d4 = 0; d4 < DHEAD / 4; ++d4) {
            float4 qv = *(const float4*)&Qs[qr][d4 * 4];
#pragma unroll
            for (int j = 0; j < 8; ++j) {
                float4 kv = *(const float4*)&Ks[sub + 8 * j][d4 * 4];
                sc[j] += qv.x * kv.x + qv.y * kv.y + qv.z * kv.z + qv.w * kv.w;
            }
        }
        if (causal) {
            int qg = q0 + qr;
#pragma unroll
            for (int j = 0; j < 8; ++j) {
                int kg = k0 + sub + 8 * j;
                if (kg > qg) sc[j] += NEGV;
            }
        }
        // online softmax (8 lanes per q-row, consecutive)
        float mt = sc[0];
#pragma unroll
        for (int j = 1; j < 8; ++j) mt = fmaxf(mt, sc[j]);
        mt = fmaxf(mt, __shfl_xor(mt, 1));
        mt = fmaxf(mt, __shfl_xor(mt, 2));
        mt = fmaxf(mt, __shfl_xor(mt, 4));
        float m_new = fmaxf(m_prev, mt);
        float fac = expf(m_prev - m_new);     // first tile: exp(-inf)=0
        float ls = 0.0f;
#pragma unroll
        for (int j = 0; j < 8; ++j) {
            float p = expf(sc[j] - m_new);
            Ps[qr][sub + 8 * j] = p;
            ls += p;
        }
        ls += __shfl_xor(ls, 1);
        ls += __shfl_xor(ls, 2);
        ls += __shfl_xor(ls, 4);
        l_prev = l_prev * fac + ls;
        m_prev = m_new;
#pragma unroll
        for (int i = 0; i < 8; ++i) o[i] *= fac;

        __syncthreads();   // Ps visible (defensive; same-wave rows, but cheap)

        // phase D: o[d = sub*8 + i] += sum_kc Ps[qr][kc] * Vs[kc][sub*8+i]
#pragma unroll
        for (int kc4 = 0; kc4 < KB / 4; ++kc4) {
            float4 pv = *(const float4*)&Ps[qr][kc4 * 4];
            float pr[4] = {pv.x, pv.y, pv.z, pv.w};
#pragma unroll
            for (int u = 0; u < 4; ++u) {
                int kc = kc4 * 4 + u;
                float4 v0 = *(const float4*)&Vs[kc][sub * 8];
                float4 v1 = *(const float4*)&Vs[kc][sub * 8 + 4];
                o[0] = fmaf(pr[u], v0.x, o[0]);
                o[1] = fmaf(pr[u], v0.y, o[1]);
                o[2] = fmaf(pr[u], v0.z, o[2]);
                o[3] = fmaf(pr[u], v0.w, o[3]);
                o[4] = fmaf(pr[u], v1.x, o[4]);
                o[5] = fmaf(pr[u], v1.y, o[5]);
                o[6] = fmaf(pr[u], v1.z, o[6]);
                o[7] = fmaf(pr[u], v1.w, o[7]);
            }
        }
    }

    float inv = 1.0f / l_prev;
    float* orow = O + (((size_t)(bb * Sq + q0 + qr)) * NHEAD + hh) * DHEAD + sub * 8;
    float4 r0 = make_float4(o[0] * inv, o[1] * inv, o[2] * inv, o[3] * inv);
    float4 r1 = make_float4(o[4] * inv, o[5] * inv, o[6] * inv, o[7] * inv);
    *(float4*)orow       = r0;
    *(float4*)(orow + 4) = r1;
}

// ---------------- host orchestration ----------------
extern "C" void kernel_launch(void* const* d_in, const int* in_sizes, int n_in,
                              void* d_out, int out_size, void* d_ws, size_t ws_size,
                              hipStream_t stream) {
    const int*   x_enc     = (const int*)d_in[0];
    const int*   x_dec     = (const int*)d_in[1];
    const float* emb_enc   = (const float*)d_in[2];
    const float* W_enc_lin = (const float*)d_in[3];
    const float* emb_dec   = (const float*)d_in[4];
    const float* W_dec_lin = (const float*)d_in[5];
    const float* p_decoder = (const float*)d_in[6];
    const float* e_pos     = (const float*)d_in[7];
    const float* p_e_q     = (const float*)d_in[8];
    const float* p_e_k     = (const float*)d_in[9];
    const float* p_e_v     = (const float*)d_in[10];
    const float* p_e_c     = (const float*)d_in[11];
    const float* p_e_ff1   = (const float*)d_in[12];
    const float* p_e_ff2   = (const float*)d_in[13];
    const float* b_e_ff1   = (const float*)d_in[14];
    const float* b_e_ff2   = (const float*)d_in[15];
    const float* e_o_bias  = (const float*)d_in[16];
    const float* e_o_scale = (const float*)d_in[17];
    const float* b_e_bias_1  = (const float*)d_in[18];
    const float* b_e_bias_2  = (const float*)d_in[19];
    const float* b_e_scale_1 = (const float*)d_in[20];
    const float* b_e_scale_2 = (const float*)d_in[21];
    const float* d_pos     = (const float*)d_in[22];
    const float* p_d_q     = (const float*)d_in[23];
    const float* p_d_k     = (const float*)d_in[24];
    const float* p_d_v     = (const float*)d_in[25];
    const float* p_d_c     = (const float*)d_in[26];
    const float* p_a_q     = (const float*)d_in[27];
    const float* p_a_k     = (const float*)d_in[28];
    const float* p_a_v     = (const float*)d_in[29];
    const float* p_a_c     = (const float*)d_in[30];
    const float* p_d_ff1   = (const float*)d_in[31];
    const float* p_d_ff2   = (const float*)d_in[32];
    const float* b_d_ff1   = (const float*)d_in[33];
    const float* b_d_ff2   = (const float*)d_in[34];
    const float* d_o_bias  = (const float*)d_in[35];
    const float* d_o_scale = (const float*)d_in[36];
    const float* b_d_bias_1  = (const float*)d_in[37];
    const float* b_d_bias_2  = (const float*)d_in[38];
    const float* b_d_bias_3  = (const float*)d_in[39];
    const float* b_d_scale_1 = (const float*)d_in[40];
    const float* b_d_scale_2 = (const float*)d_in[41];
    const float* b_d_scale_3 = (const float*)d_in[42];

    float* out = (float*)d_out;
    float* ws  = (float*)d_ws;

    // workspace layout (floats): 9 * 2M + 8M = ~104 MB
    float* b_embed   = ws;                  // enc embed, then dec embed
    float* b_x       = b_embed + SB;
    float* b_li      = b_x + SB;
    float* b_q       = b_li + SB;
    float* b_k       = b_q + SB;
    float* b_v       = b_k + SB;
    float* b_attn    = b_v + SB;
    float* b_tmp     = b_attn + SB;
    float* b_enc_out = b_tmp + SB;
    float* b_ff      = b_enc_out + SB;      // 8M floats [4096,2048]
    float* b_gather  = b_ff;                // alias: gather only used pre-layers

    const size_t HH = (size_t)HDIM * HDIM;
    const size_t HF = (size_t)HDIM * FDIM;

    auto gemm = [&](const float* A, const float* Wm, float* C, int M, int N, int K,
                    const float* bias, float alpha, int relu) {
        dim3 g(N / BN, M / BM);
        k_sgemm<<<g, dim3(256), 0, stream>>>(A, Wm, C, M, N, K, bias, alpha, relu);
    };
    auto lnadd = [&](const float* x, const float* res, const float* scale,
                     const float* bias, float* o) {
        k_lnadd<<<dim3(NROWS), dim3(256), 0, stream>>>(x, res, scale, bias, o);
    };
    auto addpos = [&](const float* x, const float* pos, float* o) {
        k_addpos<<<dim3((int)(SB / 4 / 256)), dim3(256), 0, stream>>>(
            (const float4*)x, (const float4*)pos, (float4*)o);
    };
    auto mha = [&](const float* qin, const float* kvin, const float* Wq, const float* Wk,
                   const float* Wv, const float* Wc, int causal, float* outb) {
        gemm(qin,  Wq, b_q, NROWS, HDIM, HDIM, nullptr, 0.125f, 0);  // 1/sqrt(64)
        gemm(kvin, Wk, b_k, NROWS, HDIM, HDIM, nullptr, 1.0f, 0);
        gemm(kvin, Wv, b_v, NROWS, HDIM, HDIM, nullptr, 1.0f, 0);
        dim3 g(SEQ / QB, BATCH * NHEAD);
        k_flash<<<g, dim3(256), 0, stream>>>(b_q, b_k, b_v, b_attn, SEQ, SEQ, causal);
        gemm(b_attn, Wc, outb, NROWS, HDIM, HDIM, nullptr, 1.0f, 0);
    };

    // ================= encoder =================
    k_gather<<<dim3(NROWS), dim3(EDIM), 0, stream>>>(x_enc, emb_enc, b_gather);
    gemm(b_gather, W_enc_lin, b_embed, NROWS, HDIM, EDIM, nullptr, 1.0f, 0);
    hipMemcpyAsync(b_x, b_embed, SB * sizeof(float), hipMemcpyDeviceToDevice, stream);

    for (int l = 0; l < NLAYER; ++l) {
        addpos(b_x, e_pos + (size_t)l * SEQ * HDIM, b_li);
        mha(b_li, b_li, p_e_q + l * HH, p_e_k + l * HH, p_e_v + l * HH, p_e_c + l * HH,
            0, b_tmp);
        lnadd(b_tmp, b_li, b_e_scale_1 + l * HDIM, b_e_bias_1 + l * HDIM, b_x);   // h1
        gemm(b_x, p_e_ff1 + l * HF, b_ff, NROWS, FDIM, HDIM, b_e_ff1 + l * FDIM, 1.0f, 1);
        gemm(b_ff, p_e_ff2 + l * HF, b_tmp, NROWS, HDIM, FDIM, b_e_ff2 + l * HDIM, 1.0f, 0);
        lnadd(b_tmp, b_x, b_e_scale_2 + l * HDIM, b_e_bias_2 + l * HDIM, b_x);    // h2
    }
    lnadd(b_x, b_embed, e_o_scale, e_o_bias, b_enc_out);

    // ================= decoder =================
    k_gather<<<dim3(NROWS), dim3(EDIM), 0, stream>>>(x_dec, emb_dec, b_gather);
    gemm(b_gather, W_dec_lin, b_embed, NROWS, HDIM, EDIM, nullptr, 1.0f, 0);
    hipMemcpyAsync(b_x, b_embed, SB * sizeof(float), hipMemcpyDeviceToDevice, stream);

    for (int l = 0; l < NLAYER; ++l) {
        addpos(b_x, d_pos + (size_t)l * SEQ * HDIM, b_li);
        // masked self-attention
        mha(b_li, b_li, p_d_q + l * HH, p_d_k + l * HH, p_d_v + l * HH, p_d_c + l * HH,
            1, b_tmp);
        lnadd(b_tmp, b_li, b_d_scale_1 + l * HDIM, b_d_bias_1 + l * HDIM, b_x);   // h1
        // cross-attention (kv from encoder output)
        mha(b_x, b_enc_out, p_a_q + l * HH, p_a_k + l * HH, p_a_v + l * HH, p_a_c + l * HH,
            0, b_tmp);
        lnadd(b_tmp, b_x, b_d_scale_2 + l * HDIM, b_d_bias_2 + l * HDIM, b_x);    // h2
        // feed-forward
        gemm(b_x, p_d_ff1 + l * HF, b_ff, NROWS, FDIM, HDIM, b_d_ff1 + l * FDIM, 1.0f, 1);
        gemm(b_ff, p_d_ff2 + l * HF, b_tmp, NROWS, HDIM, FDIM, b_d_ff2 + l * HDIM, 1.0f, 0);
        lnadd(b_tmp, b_x, b_d_scale_3 + l * HDIM, b_d_bias_3 + l * HDIM, b_x);    // h3
    }
    lnadd(b_x, b_embed, d_o_scale, d_o_bias, b_tmp);   // dec_out

    // logits = dec_out @ p_decoder  -> [4096, 32000]
    gemm(b_tmp, p_decoder, out, NROWS, VD, HDIM, nullptr, 1.0f, 0);
}